// Round 1
// baseline (1005.430 us; speedup 1.0000x reference)
//
#include <hip/hip_runtime.h>
#include <math.h>

#define K1 128   // input feature dim
#define C  64    // hidden == output channels

__device__ __forceinline__ void atomAddF(float* p, float v) {
    // HW f32 atomic (global_atomic_add_f32); plain atomicAdd may emit a CAS loop
    unsafeAtomicAdd(p, v);
}

// ---- edge dtype detection: int64 edges have all-zero high words ----
__global__ void detect_kernel(const int* __restrict__ e, int twoE, int* __restrict__ flag) {
    __shared__ int nz;
    if (threadIdx.x == 0) nz = 0;
    __syncthreads();
    int nchk = twoE / 2; if (nchk > 4096) nchk = 4096;
    int bad = 0;
    for (int i = threadIdx.x; i < nchk; i += blockDim.x)
        if (e[2 * i + 1] != 0) bad = 1;
    if (bad) atomicOr(&nz, 1);
    __syncthreads();
    if (threadIdx.x == 0) *flag = nz ? 0 : 1;   // 1 => int64
}

__global__ void convert_kernel(const void* __restrict__ ein, int twoE,
                               const int* __restrict__ flag, int* __restrict__ eout) {
    int is64 = *flag;
    int i = blockIdx.x * blockDim.x + threadIdx.x;
    int stride = gridDim.x * blockDim.x;
    if (is64) {
        const long long* p = (const long long*)ein;
        for (; i < twoE; i += stride) eout[i] = (int)p[i];
    } else {
        const int* p = (const int*)ein;
        for (; i < twoE; i += stride) eout[i] = p[i];
    }
}

// ---- degree / rsqrt ----
__global__ void deg_init_kernel(float* __restrict__ deg, int n) {
    for (int i = blockIdx.x * blockDim.x + threadIdx.x; i < n; i += gridDim.x * blockDim.x)
        deg[i] = 1.0f;   // self-loop
}

__global__ void deg_count_kernel(const int* __restrict__ dst, int E, float* __restrict__ deg) {
    for (int e = blockIdx.x * blockDim.x + threadIdx.x; e < E; e += gridDim.x * blockDim.x)
        atomAddF(&deg[dst[e]], 1.0f);
}

__global__ void deg_rsqrt_kernel(float* __restrict__ deg, int n) {
    for (int i = blockIdx.x * blockDim.x + threadIdx.x; i < n; i += gridDim.x * blockDim.x)
        deg[i] = rsqrtf(deg[i]);
}

// ---- g = (X @ W) * dinv[row]; written to G and G2 (G2 = scatter buf init w/ self-loop) ----
// One wave handles R rows; lane = output column. Row addresses are wave-uniform
// (readfirstlane) so X loads become scalar (SMEM) loads; W is staged in LDS.
template<int K, int R>
__global__ __launch_bounds__(256) void gemm_kernel(const float* __restrict__ X,
        const float* __restrict__ W, const float* __restrict__ dinv,
        float* __restrict__ G, float* __restrict__ G2, int n)
{
    __shared__ float Ws[K * C];
    for (int i = threadIdx.x; i < K * C; i += 256) Ws[i] = W[i];
    __syncthreads();
    const int lane = threadIdx.x & 63;
    const int wave = __builtin_amdgcn_readfirstlane((int)(threadIdx.x >> 6));
    const int waves = gridDim.x * 4;
    for (int base = (blockIdx.x * 4 + wave) * R; base < n; base += waves * R) {
        float acc[R];
        #pragma unroll
        for (int r = 0; r < R; ++r) acc[r] = 0.0f;
        if (base + R <= n) {
            for (int k = 0; k < K; ++k) {
                float w = Ws[k * C + lane];          // 2-way bank alias: free
                #pragma unroll
                for (int r = 0; r < R; ++r)
                    acc[r] = fmaf(X[(size_t)(base + r) * K + k], w, acc[r]);
            }
            #pragma unroll
            for (int r = 0; r < R; ++r) {
                float v = acc[r] * dinv[base + r];
                G [(size_t)(base + r) * C + lane] = v;
                G2[(size_t)(base + r) * C + lane] = v;
            }
        } else {
            for (int r = 0; r < R; ++r) {
                if (base + r >= n) break;
                float a = 0.0f;
                for (int k = 0; k < K; ++k)
                    a = fmaf(X[(size_t)(base + r) * K + k], Ws[k * C + lane], a);
                float v = a * dinv[base + r];
                G [(size_t)(base + r) * C + lane] = v;
                G2[(size_t)(base + r) * C + lane] = v;
            }
        }
    }
}

// ---- edge scatter-add: one wave per edge, lane = channel ----
__global__ __launch_bounds__(256) void agg_kernel(const int* __restrict__ src,
        const int* __restrict__ dst, int E,
        const float* __restrict__ G, float* __restrict__ AGG)
{
    const int lane = threadIdx.x & 63;
    int w0 = __builtin_amdgcn_readfirstlane((int)(blockIdx.x * 4 + (threadIdx.x >> 6)));
    int nw = gridDim.x * 4;
    for (int e = w0; e < E; e += nw) {
        int s = src[e], d = dst[e];
        float v = G[(size_t)s * C + lane];
        atomAddF(&AGG[(size_t)d * C + lane], v);
    }
}

// ---- x2 = relu(agg * dinv[row] + b1), in place ----
__global__ void relu_bias_kernel(float* __restrict__ A, const float* __restrict__ dinv,
                                 const float* __restrict__ b, int n) {
    int total = n * C;
    for (int i = blockIdx.x * blockDim.x + threadIdx.x; i < total; i += gridDim.x * blockDim.x) {
        int row = i >> 6, col = i & 63;
        float v = fmaf(A[i], dinv[row], b[col]);
        A[i] = v > 0.0f ? v : 0.0f;
    }
}

// ---- y = out*dinv + b2, then log_softmax over 64 cols (one wave per row) ----
__global__ __launch_bounds__(256) void logsoftmax_kernel(float* __restrict__ Out,
        const float* __restrict__ dinv, const float* __restrict__ b, int n) {
    const int lane = threadIdx.x & 63;
    int w0 = __builtin_amdgcn_readfirstlane((int)(blockIdx.x * 4 + (threadIdx.x >> 6)));
    int nw = gridDim.x * 4;
    float bias = b[lane];
    for (int row = w0; row < n; row += nw) {
        float y = fmaf(Out[(size_t)row * C + lane], dinv[row], bias);
        float m = y;
        #pragma unroll
        for (int off = 32; off > 0; off >>= 1)
            m = fmaxf(m, __shfl_xor(m, off, 64));
        float ex = expf(y - m);
        float l = ex;
        #pragma unroll
        for (int off = 32; off > 0; off >>= 1)
            l += __shfl_xor(l, off, 64);
        Out[(size_t)row * C + lane] = y - m - logf(l);
    }
}

extern "C" void kernel_launch(void* const* d_in, const int* in_sizes, int n_in,
                              void* d_out, int out_size, void* d_ws, size_t ws_size,
                              hipStream_t stream)
{
    const float* X  = (const float*)d_in[0];
    const void*  EI = d_in[1];
    const float* W1 = (const float*)d_in[3];
    const float* b1 = (const float*)d_in[4];
    const float* W2 = (const float*)d_in[5];
    const float* b2 = (const float*)d_in[6];
    float* Out = (float*)d_out;

    const int n    = in_sizes[0] / K1;
    const int E    = in_sizes[1] / 2;
    const int twoE = 2 * E;

    // workspace layout (all 16B-aligned for these sizes)
    char* ws = (char*)d_ws;
    int*   edges = (int*)ws;
    size_t off = (size_t)twoE * sizeof(int);
    float* dinv = (float*)(ws + off); off += (size_t)n * sizeof(float);
    float* G    = (float*)(ws + off); off += (size_t)n * C * sizeof(float);
    float* AGG  = (float*)(ws + off); off += (size_t)n * C * sizeof(float);
    int*   flag = (int*)(ws + off);

    const int* srcp = edges;
    const int* dstp = edges + E;

    hipLaunchKernelGGL(detect_kernel,  dim3(1),    dim3(256), 0, stream, (const int*)EI, twoE, flag);
    hipLaunchKernelGGL(convert_kernel, dim3(2048), dim3(256), 0, stream, EI, twoE, flag, edges);

    hipLaunchKernelGGL(deg_init_kernel,  dim3(512),  dim3(256), 0, stream, dinv, n);
    hipLaunchKernelGGL(deg_count_kernel, dim3(2048), dim3(256), 0, stream, dstp, E, dinv);
    hipLaunchKernelGGL(deg_rsqrt_kernel, dim3(512),  dim3(256), 0, stream, dinv, n);

    // layer 1: G = (X@W1)*dinv ; AGG initialized with self-loop term
    hipLaunchKernelGGL((gemm_kernel<K1, 8>), dim3(2048), dim3(256), 0, stream, X, W1, dinv, G, AGG, n);
    hipLaunchKernelGGL(agg_kernel, dim3(8192), dim3(256), 0, stream, srcp, dstp, E, G, AGG);
    hipLaunchKernelGGL(relu_bias_kernel, dim3(2048), dim3(256), 0, stream, AGG, dinv, b1, n);

    // layer 2: G = (X2@W2)*dinv ; Out initialized with self-loop term
    hipLaunchKernelGGL((gemm_kernel<C, 8>), dim3(2048), dim3(256), 0, stream, AGG, W2, dinv, G, Out, n);
    hipLaunchKernelGGL(agg_kernel, dim3(8192), dim3(256), 0, stream, srcp, dstp, E, G, Out);
    hipLaunchKernelGGL(logsoftmax_kernel, dim3(2048), dim3(256), 0, stream, Out, dinv, b2, n);
}

// Round 3
// 583.364 us; speedup vs baseline: 1.7235x; 1.7235x over previous
//
#include <hip/hip_runtime.h>
#include <math.h>

#define K1 128   // input feature dim
#define C  64    // hidden == output channels
#define SCAN_B 1024

// ---- edge dtype detection: int64 edges have all-zero high words ----
__global__ void detect_kernel(const int* __restrict__ e, int twoE, int* __restrict__ flag) {
    __shared__ int nz;
    if (threadIdx.x == 0) nz = 0;
    __syncthreads();
    int nchk = twoE / 2; if (nchk > 4096) nchk = 4096;
    int bad = 0;
    for (int i = threadIdx.x; i < nchk; i += blockDim.x)
        if (e[2 * i + 1] != 0) bad = 1;
    if (bad) atomicOr(&nz, 1);
    __syncthreads();
    if (threadIdx.x == 0) *flag = nz ? 0 : 1;   // 1 => int64
}

__global__ void convert_kernel(const void* __restrict__ ein, int twoE,
                               const int* __restrict__ flag, int* __restrict__ eout) {
    int is64 = *flag;
    int i = blockIdx.x * blockDim.x + threadIdx.x;
    int stride = gridDim.x * blockDim.x;
    if (is64) {
        const long long* p = (const long long*)ein;
        for (; i < twoE; i += stride) eout[i] = (int)p[i];
    } else {
        const int* p = (const int*)ein;
        for (; i < twoE; i += stride) eout[i] = p[i];
    }
}

// ---- degree histogram (int) ----
__global__ void zero_kernel(int* __restrict__ p, int n) {
    for (int i = blockIdx.x * blockDim.x + threadIdx.x; i < n; i += gridDim.x * blockDim.x)
        p[i] = 0;
}

__global__ void cnt_kernel(const int* __restrict__ dst, int E, int* __restrict__ cnt) {
    for (int e = blockIdx.x * blockDim.x + threadIdx.x; e < E; e += gridDim.x * blockDim.x)
        atomicAdd(&cnt[dst[e]], 1);
}

__global__ void dinv_kernel(const int* __restrict__ cnt, float* __restrict__ dinv, int n) {
    for (int i = blockIdx.x * blockDim.x + threadIdx.x; i < n; i += gridDim.x * blockDim.x)
        dinv[i] = rsqrtf((float)(cnt[i] + 1));   // +1 = self-loop
}

// ---- exclusive scan of cnt -> rowptr (3 phases) ----
__global__ __launch_bounds__(SCAN_B) void scan1_kernel(const int* __restrict__ cnt, int n,
        int* __restrict__ ex, int* __restrict__ bsum) {
    __shared__ int s[SCAN_B];
    int i = blockIdx.x * SCAN_B + threadIdx.x;
    int v = (i < n) ? cnt[i] : 0;
    s[threadIdx.x] = v;
    __syncthreads();
    for (int off = 1; off < SCAN_B; off <<= 1) {
        int t = (threadIdx.x >= off) ? s[threadIdx.x - off] : 0;
        __syncthreads();
        s[threadIdx.x] += t;
        __syncthreads();
    }
    if (i < n) ex[i] = s[threadIdx.x] - v;            // exclusive within block
    if (threadIdx.x == SCAN_B - 1) bsum[blockIdx.x] = s[SCAN_B - 1];
}

__global__ void scan2_kernel(int* __restrict__ bsum, int nb) {
    // single wave: 64-wide shuffle scan over chunks
    const int lane = threadIdx.x & 63;
    int acc = 0;
    for (int base = 0; base < nb; base += 64) {
        int v = (base + lane < nb) ? bsum[base + lane] : 0;
        int sc = v;
        #pragma unroll
        for (int off = 1; off < 64; off <<= 1) {
            int t = __shfl_up(sc, off, 64);
            if (lane >= off) sc += t;
        }
        if (base + lane < nb) bsum[base + lane] = acc + sc - v;   // exclusive
        acc += __shfl(sc, 63, 64);
    }
}

__global__ void scan3_kernel(int* __restrict__ ex, const int* __restrict__ bsum,
                             int* __restrict__ fill, int n, int Etot) {
    for (int i = blockIdx.x * blockDim.x + threadIdx.x; i < n; i += gridDim.x * blockDim.x) {
        int v = ex[i] + bsum[i / SCAN_B];
        ex[i] = v;
        fill[i] = v;
    }
    if (blockIdx.x == 0 && threadIdx.x == 0) ex[n] = Etot;
}

// ---- scatter edges into CSR order (position via atomic on fill) ----
__global__ void scatter_kernel(const int* __restrict__ src, const int* __restrict__ dst,
                               int E, int* __restrict__ fill, int* __restrict__ csr) {
    for (int e = blockIdx.x * blockDim.x + threadIdx.x; e < E; e += gridDim.x * blockDim.x) {
        int pos = atomicAdd(&fill[dst[e]], 1);
        csr[pos] = src[e];
    }
}

// ---- G = (X @ W) * dinv[row]; one wave per R rows, lane = out col ----
template<int K, int R>
__global__ __launch_bounds__(256) void gemm_kernel(const float* __restrict__ X,
        const float* __restrict__ W, const float* __restrict__ dinv,
        float* __restrict__ G, int n)
{
    __shared__ float Ws[K * C];
    for (int i = threadIdx.x; i < K * C; i += 256) Ws[i] = W[i];
    __syncthreads();
    const int lane = threadIdx.x & 63;
    const int wave = __builtin_amdgcn_readfirstlane((int)(threadIdx.x >> 6));
    const int waves = gridDim.x * 4;
    for (int base = (blockIdx.x * 4 + wave) * R; base < n; base += waves * R) {
        float acc[R];
        #pragma unroll
        for (int r = 0; r < R; ++r) acc[r] = 0.0f;
        if (base + R <= n) {
            for (int k = 0; k < K; ++k) {
                float w = Ws[k * C + lane];
                #pragma unroll
                for (int r = 0; r < R; ++r)
                    acc[r] = fmaf(X[(size_t)(base + r) * K + k], w, acc[r]);
            }
            #pragma unroll
            for (int r = 0; r < R; ++r)
                G[(size_t)(base + r) * C + lane] = acc[r] * dinv[base + r];
        } else {
            for (int r = 0; r < R; ++r) {
                if (base + r >= n) break;
                float a = 0.0f;
                for (int k = 0; k < K; ++k)
                    a = fmaf(X[(size_t)(base + r) * K + k], Ws[k * C + lane], a);
                G[(size_t)(base + r) * C + lane] = a * dinv[base + r];
            }
        }
    }
}

// ---- CSR gather: one wave per dst row; MODE 0 = relu+bias, 1 = bias+logsoftmax ----
template<int MODE>
__global__ __launch_bounds__(256) void gather_kernel(const int* __restrict__ rowptr,
        const int* __restrict__ csr, const float* __restrict__ G,
        const float* __restrict__ dinv, const float* __restrict__ bias,
        float* __restrict__ Out, int n)
{
    const int lane = threadIdx.x & 63;
    const int v = __builtin_amdgcn_readfirstlane((int)(blockIdx.x * 4 + (threadIdx.x >> 6)));
    if (v >= n) return;
    const int start = __builtin_amdgcn_readfirstlane(rowptr[v]);
    const int end   = __builtin_amdgcn_readfirstlane(rowptr[v + 1]);
    float a0 = G[(size_t)v * C + lane];   // self-loop term
    float a1 = 0.f, a2 = 0.f, a3 = 0.f;
    for (int base = start; base < end; base += 64) {
        int m = end - base; if (m > 64) m = 64;
        int idx = (lane < m) ? csr[base + lane] : 0;
        int j = 0;
        for (; j + 4 <= m; j += 4) {
            int s0 = __shfl(idx, j,     64);
            int s1 = __shfl(idx, j + 1, 64);
            int s2 = __shfl(idx, j + 2, 64);
            int s3 = __shfl(idx, j + 3, 64);
            a0 += G[(size_t)s0 * C + lane];
            a1 += G[(size_t)s1 * C + lane];
            a2 += G[(size_t)s2 * C + lane];
            a3 += G[(size_t)s3 * C + lane];
        }
        for (; j < m; ++j) {
            int s = __shfl(idx, j, 64);
            a0 += G[(size_t)s * C + lane];
        }
    }
    float acc = (a0 + a1) + (a2 + a3);
    float y = fmaf(acc, dinv[v], bias[lane]);
    if (MODE == 0) {
        Out[(size_t)v * C + lane] = y > 0.f ? y : 0.f;
    } else {
        float mx = y;
        #pragma unroll
        for (int off = 32; off > 0; off >>= 1) mx = fmaxf(mx, __shfl_xor(mx, off, 64));
        float ex = expf(y - mx);
        float l = ex;
        #pragma unroll
        for (int off = 32; off > 0; off >>= 1) l += __shfl_xor(l, off, 64);
        Out[(size_t)v * C + lane] = y - mx - logf(l);
    }
}

static inline size_t align16(size_t x) { return (x + 15) & ~(size_t)15; }

extern "C" void kernel_launch(void* const* d_in, const int* in_sizes, int n_in,
                              void* d_out, int out_size, void* d_ws, size_t ws_size,
                              hipStream_t stream)
{
    const float* X  = (const float*)d_in[0];
    const void*  EI = d_in[1];
    const float* W1 = (const float*)d_in[3];
    const float* b1 = (const float*)d_in[4];
    const float* W2 = (const float*)d_in[5];
    const float* b2 = (const float*)d_in[6];
    float* Out = (float*)d_out;

    const int n    = in_sizes[0] / K1;
    const int E    = in_sizes[1] / 2;
    const int twoE = 2 * E;
    const int nb   = (n + SCAN_B - 1) / SCAN_B;

    // workspace layout — total ~46.8 MB (R1's working layout was 64.4 MB).
    // Layer-1 activations H live in d_out (N*C f32 == out_size, fully
    // rewritten by the final gather) to stay well under ws_size.
    char* ws = (char*)d_ws;
    size_t off = 0;
    int*   edges  = (int*)(ws + off); off = align16(off + (size_t)twoE * 4);
    int*   csr    = (int*)(ws + off); off = align16(off + (size_t)E * 4);
    int*   rowptr = (int*)(ws + off); off = align16(off + (size_t)(n + 1) * 4);
    int*   cnt    = (int*)(ws + off); off = align16(off + (size_t)n * 4);
    int*   bsum   = (int*)(ws + off); off = align16(off + (size_t)(nb + 1) * 4);
    int*   flag   = (int*)(ws + off); off = align16(off + 16);
    float* dinv   = (float*)(ws + off); off = align16(off + (size_t)n * 4);
    float* G      = (float*)(ws + off); off = align16(off + (size_t)n * C * 4);
    int*   fill   = cnt;               // cnt is dead after scan1/dinv
    float* H      = Out;               // layer-1 output staged in d_out

    const int* srcp = edges;
    const int* dstp = edges + E;

    hipLaunchKernelGGL(detect_kernel,  dim3(1),    dim3(256), 0, stream, (const int*)EI, twoE, flag);
    hipLaunchKernelGGL(convert_kernel, dim3(4096), dim3(256), 0, stream, EI, twoE, flag, edges);

    // CSR build + normalization
    hipLaunchKernelGGL(zero_kernel, dim3(512),  dim3(256), 0, stream, cnt, n);
    hipLaunchKernelGGL(cnt_kernel,  dim3(2048), dim3(256), 0, stream, dstp, E, cnt);
    hipLaunchKernelGGL(dinv_kernel, dim3(512),  dim3(256), 0, stream, cnt, dinv, n);
    hipLaunchKernelGGL(scan1_kernel, dim3(nb), dim3(SCAN_B), 0, stream, cnt, n, rowptr, bsum);
    hipLaunchKernelGGL(scan2_kernel, dim3(1),  dim3(64),     0, stream, bsum, nb);
    hipLaunchKernelGGL(scan3_kernel, dim3(1024), dim3(256),  0, stream, rowptr, bsum, fill, n, E);
    hipLaunchKernelGGL(scatter_kernel, dim3(2048), dim3(256), 0, stream, srcp, dstp, E, fill, csr);

    const int ngb = (n + 3) / 4;   // one wave per row

    // layer 1: G = (X@W1)*dinv ; H = relu(gather(G)*dinv + b1)
    hipLaunchKernelGGL((gemm_kernel<K1, 8>), dim3(2048), dim3(256), 0, stream, X, W1, dinv, G, n);
    hipLaunchKernelGGL((gather_kernel<0>), dim3(ngb), dim3(256), 0, stream, rowptr, csr, G, dinv, b1, H, n);

    // layer 2: G = (H@W2)*dinv ; Out = log_softmax(gather(G)*dinv + b2)
    hipLaunchKernelGGL((gemm_kernel<C, 8>), dim3(2048), dim3(256), 0, stream, H, W2, dinv, G, n);
    hipLaunchKernelGGL((gather_kernel<1>), dim3(ngb), dim3(256), 0, stream, rowptr, csr, G, dinv, b2, Out, n);
}